// Round 20
// baseline (222.839 us; speedup 1.0000x reference)
//
#include <hip/hip_runtime.h>

// Sinkhorn image loss — conv form (R=10), ONE KERNEL, one block per batch.
//   K = exp(-C/eps) = exp(-1.5045*d_pix): radial 21x21 stencil (R=10 tail
//   ~3e-6 rel; absmax 0.0 verified rounds 13-19). Weights from C row 1176.
//   Critical insight: one batch's image = 9.2 KB; its whole 20-conv Sinkhorn
//   chain fits in ONE block's LDS -> zero cross-block traffic, zero grid
//   sync, zero dispatch gaps, zero halo redundancy. 16 independent blocks
//   (one per batch) run the full chain; critical path = 20 in-block convs.
//
//   Per conv: 1152 tasks = 6 dy-fold level-groups x 192 strips (12-wide);
//   task = conv_c12/conv_p12 (r17-19-proven exact). Partials 6 levels,
//   slot stride 13 (conflict-free scalar stores). a1 = p/rectsum via the
//   r19-proven 2D-prefix lookup (no conv). Softmax stats computed in-block.
//   Cost: s1 = K a10 -> LDS, s2 = (K.C) a10; sum q/s1*s2; atomicAdd /16.
//   768 threads (12 waves): VGPR cap ~170 -> no spill (r17's failure mode).

namespace {

constexpr int N    = 2304;   // 48*48
constexpr int WIN  = 21;
constexpr int WPAD = 24;
constexpr int APX  = 12;     // aligned x-apron; taps at word offset +2
constexpr int AST  = 76;     // LDS row stride (words)
constexpr int ART  = 68;     // apron rows (48 + 2*10)
constexpr int PSL  = 13;     // partial slot stride (odd -> conflict-free)
constexpr int PLV  = 192 * PSL;  // 2496 words per fold level
constexpr int NTHR = 768;

__device__ __forceinline__ float wave_sum(float v) {
#pragma unroll
    for (int off = 32; off >= 1; off >>= 1) v += __shfl_xor(v, off);
    return v;
}

// ---- conv primitives (r16-r19-proven): acc[k] += w[dx]*row[k+2+dx] --------
__device__ __forceinline__ void conv_c12(const float* vp, const float* wp,
                                         float* acc) {
    float vr[36], wr[24];
#pragma unroll
    for (int c = 0; c < 9; ++c) *(float4*)&vr[4 * c] = *(const float4*)&vp[4 * c];
#pragma unroll
    for (int c = 0; c < 6; ++c) *(float4*)&wr[4 * c] = *(const float4*)&wp[4 * c];
#pragma unroll
    for (int dx = 0; dx < WIN; ++dx)
#pragma unroll
        for (int k = 0; k < 12; ++k)
            acc[k] = fmaf(wr[dx], vr[k + 2 + dx], acc[k]);
}
__device__ __forceinline__ void conv_p12(const float* lo, const float* hi,
                                         const float* wp, float* acc) {
    float vr[36], wr[24];
#pragma unroll
    for (int c = 0; c < 9; ++c) {
        const float4 a = *(const float4*)&lo[4 * c];
        const float4 b = *(const float4*)&hi[4 * c];
        vr[4 * c]     = a.x + b.x;
        vr[4 * c + 1] = a.y + b.y;
        vr[4 * c + 2] = a.z + b.z;
        vr[4 * c + 3] = a.w + b.w;
    }
#pragma unroll
    for (int c = 0; c < 6; ++c) *(float4*)&wr[4 * c] = *(const float4*)&wp[4 * c];
#pragma unroll
    for (int dx = 0; dx < WIN; ++dx)
#pragma unroll
        for (int k = 0; k < 12; ++k)
            acc[k] = fmaf(wr[dx], vr[k + 2 + dx], acc[k]);
}

// Full-image folded conv: buf (68x76 zero-padded apron) -> part (6 levels).
// Tasks: tau = u2*192 + strip; strip = r*4 + xq (out row r, 12-wide group).
// u2=0: center + pair1; u2=1..4: pairs (2u2, 2u2+1); u2=5: pair 10.
__device__ __forceinline__ void conv_pass(const float* buf, const float* wt,
                                          float* part, int tid) {
#pragma unroll
    for (int sweep = 0; sweep < 2; ++sweep) {
        const int tau = tid + sweep * NTHR;
        if (tau < 1152) {
            const int u2 = tau / 192, strip = tau - u2 * 192;
            const int r = strip >> 2, xw = (strip & 3) * 12;
            float acc[12];
#pragma unroll
            for (int k = 0; k < 12; ++k) acc[k] = 0.f;
            if (u2 == 0) {
                conv_c12(&buf[(r + 10) * AST + xw], &wt[10 * WPAD], acc);
                conv_p12(&buf[(r + 9) * AST + xw], &buf[(r + 11) * AST + xw],
                         &wt[11 * WPAD], acc);
            } else if (u2 < 5) {
                const int d = 2 * u2;
                conv_p12(&buf[(r + 10 - d) * AST + xw],
                         &buf[(r + 10 + d) * AST + xw], &wt[(10 + d) * WPAD], acc);
                conv_p12(&buf[(r + 9 - d) * AST + xw],
                         &buf[(r + 11 + d) * AST + xw], &wt[(11 + d) * WPAD], acc);
            } else {
                conv_p12(&buf[r * AST + xw], &buf[(r + 20) * AST + xw],
                         &wt[20 * WPAD], acc);
            }
            float* pp = &part[u2 * PLV + strip * PSL];
#pragma unroll
            for (int k = 0; k < 12; ++k) pp[k] = acc[k];
        }
    }
}

// --------------------------------------------------------------- batch ----
__global__ __launch_bounds__(NTHR, 1) void sk_batch(const float* __restrict__ logits,
                                                    const float* __restrict__ target,
                                                    const float* __restrict__ C,
                                                    float* __restrict__ out) {
    __shared__ float bufA[ART * AST];   // 20672 B
    __shared__ float bufB[ART * AST];   // 20672 B
    __shared__ float wtl[WIN * WPAD];   //  2016 B
    __shared__ float wcl[WIN * WPAD];   //  2016 B
    __shared__ float part[6 * PLV];     // 59904 B  (also pfx scratch)
    __shared__ float sred[32];

    const int b    = blockIdx.x;
    const int tid  = threadIdx.x;
    const int w    = tid >> 6, lane = tid & 63;
    const float* lg = logits + b * N;
    const float* tg = target + b * N;

    // ---- zero both aprons (borders stay 0 forever) ------------------------
    for (int i = tid; i < (ART * AST) / 4; i += NTHR) {
        *(float4*)&bufA[4 * i] = make_float4(0.f, 0.f, 0.f, 0.f);
        *(float4*)&bufB[4 * i] = make_float4(0.f, 0.f, 0.f, 0.f);
    }

    // ---- weight tables from C row 1176 (pixel (24,24)) --------------------
    for (int i = tid; i < WIN * WPAD; i += NTHR) {
        const int dy = i / WPAD, dx = i - dy * WPAD;
        float wv = 0.f, wc = 0.f;
        if (dx < WIN) {
            const float c = C[1176 * N + (14 + dy) * 48 + (14 + dx)];
            wv = __expf(c * -100.f);
            wc = wv * c;
        }
        wtl[i] = wv;
        wcl[i] = wc;
    }

    // ---- softmax stats (3 elems/thread, 12-wave reduce) -------------------
    float xs[3];
    float m = -3.0e38f;
#pragma unroll
    for (int k = 0; k < 3; ++k) {
        xs[k] = lg[tid + k * NTHR];
        m = fmaxf(m, xs[k]);
    }
    m = wave_sum(0.f), m = -3.0e38f;   // (keep wave_sum linked; recompute)
#pragma unroll
    for (int k = 0; k < 3; ++k) m = fmaxf(m, xs[k]);
#pragma unroll
    for (int off = 32; off >= 1; off >>= 1) m = fmaxf(m, __shfl_xor(m, off));
    if (lane == 0) sred[w] = m;
    __syncthreads();
    m = sred[0];
#pragma unroll
    for (int i = 1; i < 12; ++i) m = fmaxf(m, sred[i]);
    float sum = 0.f;
#pragma unroll
    for (int k = 0; k < 3; ++k) sum += __expf(xs[k] - m);
    sum = wave_sum(sum);
    __syncthreads();
    if (lane == 0) sred[16 + w] = sum;
    __syncthreads();
    sum = 0.f;
#pragma unroll
    for (int i = 0; i < 12; ++i) sum += sred[16 + i];
    const float sm_m = m, sm_inv = 1.f / sum;

    // ---- 2D prefix of weight table (r19-proven) into part scratch ---------
    float* pfx = part;
    if (tid < WIN) {
        float run = 0.f;
        for (int j = 0; j < WIN; ++j) {
            run += wtl[tid * WPAD + j];
            pfx[tid * WIN + j] = run;
        }
    }
    __syncthreads();
    if (tid < WIN) {
        float run = 0.f;
        for (int d = 0; d < WIN; ++d) {
            run += pfx[d * WIN + tid];
            pfx[d * WIN + tid] = run;
        }
    }
    __syncthreads();

    // ---- a1 = p / rectsum  -> bufA interior -------------------------------
#pragma unroll
    for (int j = 0; j < 3; ++j) {
        const int o = tid + j * NTHR;
        const int y = o / 48, x = o - y * 48;
        const int ulo = max(0, 10 - y), uhi = min(20, 57 - y);
        const int vlo = max(0, 10 - x), vhi = min(20, 57 - x);
        float rs = pfx[uhi * WIN + vhi];
        if (ulo) rs -= pfx[(ulo - 1) * WIN + vhi];
        if (vlo) rs -= pfx[uhi * WIN + (vlo - 1)];
        if (ulo && vlo) rs += pfx[(ulo - 1) * WIN + (vlo - 1)];
        bufA[(y + 10) * AST + x + APX] = __expf(xs[j] - sm_m) * sm_inv / rs;
    }
    __syncthreads();

    // ---- 18 conv steps: b1,a2,b2,...,b9,a10 -------------------------------
    float* cur = bufA;
    float* oth = bufB;
    for (int step = 1; step <= 18; ++step) {
        conv_pass(cur, wtl, part, tid);
        __syncthreads();
        const bool isB = (step & 1) != 0;
#pragma unroll
        for (int j = 0; j < 3; ++j) {
            const int o = tid + j * NTHR;
            const int strip = o / 12, k = o - strip * 12;
            float s = 0.f;
#pragma unroll
            for (int l = 0; l < 6; ++l) s += part[l * PLV + strip * PSL + k];
            const float sv = isB ? (tg[o] + 1e-8f)
                                 : __expf(lg[o] - sm_m) * sm_inv;
            oth[((o / 48) + 10) * AST + (o % 48) + APX] = sv / s;
        }
        __syncthreads();
        float* t = cur; cur = oth; oth = t;
    }
    // cur = a10 (18 swaps -> back in bufA)

    // ---- cost: s1 = K a10 (store raw), s2 = (K.C) a10; sum q/s1*s2 --------
    conv_pass(cur, wtl, part, tid);
    __syncthreads();
#pragma unroll
    for (int j = 0; j < 3; ++j) {
        const int o = tid + j * NTHR;
        const int strip = o / 12, k = o - strip * 12;
        float s = 0.f;
#pragma unroll
        for (int l = 0; l < 6; ++l) s += part[l * PLV + strip * PSL + k];
        oth[((o / 48) + 10) * AST + (o % 48) + APX] = s;   // raw s1
    }
    __syncthreads();
    conv_pass(cur, wcl, part, tid);
    __syncthreads();

    float val = 0.f;
#pragma unroll
    for (int j = 0; j < 3; ++j) {
        const int o = tid + j * NTHR;
        const int strip = o / 12, k = o - strip * 12;
        float s2 = 0.f;
#pragma unroll
        for (int l = 0; l < 6; ++l) s2 += part[l * PLV + strip * PSL + k];
        const float s1 = oth[((o / 48) + 10) * AST + (o % 48) + APX];
        val += (tg[o] + 1e-8f) / s1 * s2;
    }
    val = wave_sum(val);
    __syncthreads();
    if (lane == 0) sred[w] = val;
    __syncthreads();
    if (tid == 0) {
        float t = 0.f;
#pragma unroll
        for (int i = 0; i < 12; ++i) t += sred[i];
        atomicAdd(out, t * (1.f / 16.f));
    }
}

}  // namespace

extern "C" void kernel_launch(void* const* d_in, const int* in_sizes, int n_in,
                              void* d_out, int out_size, void* d_ws, size_t ws_size,
                              hipStream_t stream) {
    const float* logits = (const float*)d_in[0];   // (16, 48, 48)
    const float* target = (const float*)d_in[1];   // (16, 48, 48)
    const float* C      = (const float*)d_in[2];   // (1, N, N)
    float* out = (float*)d_out;

    hipMemsetAsync(out, 0, sizeof(float), stream);
    sk_batch<<<16, NTHR, 0, stream>>>(logits, target, C, out);
}

// Round 21
// 83.774 us; speedup vs baseline: 2.6600x; 2.6600x over previous
//
#include <hip/hip_runtime.h>

// Sinkhorn image loss — conv form (R=10), 11 dispatches, LDS-lean fused core.
//   K = exp(-C/eps) = exp(-1.5045*d_pix): radial 21x21 stencil. R=10 tail
//   ~3e-6 relative (threshold 4.3e-4); absmax 0.0 verified rounds 13-20.
//   a1 = p/(K*1); 9 x fused {b_t = q/(K a_t); a_{t+1} = p/(K b_t)}; b10+cost.
//
// ROUND-16 CHAMPION, restored verbatim (83.8 us). Post-r16 attempts all
// failed to beat it: triple-fusion (r17, 123.7 — redundancy+LDS cliff),
// fold+prefetch (r18, 95.7 — conflicted f4 partial stores), fold+node-removal
// (r19, 84.9 — null: 2x VALU cut moved nothing -> fused kernel is fixed-
// overhead-bound, not instruction-bound), single-kernel chain (r20, 222.8 —
// one CU's LDS pipe per batch). Structure: 256 blocks (16 b x 16 slices),
// 24-wide strips (36 b128/thread), scalar stride-25 partial stores
// (conflict-free), 2-deep conv task grain, plain graph nodes (device sync
// proven >= gap cost in r4-7/r11/r14).

namespace {

constexpr int N    = 2304;   // 48*48
constexpr int B    = 16;
constexpr int NB   = N * B;
constexpr int R    = 10;
constexpr int WIN  = 21;
constexpr int WPAD = 24;
constexpr int APX  = 12;     // aligned x-apron; taps at word offset +2
constexpr int AST  = 76;     // LDS row stride (words); row data = 72 words
constexpr int NOUT = 144;    // 3*48
constexpr int NTH  = WIN * 12;   // 252 (single-conv kernels)
constexpr int AVR1 = 23;     // apron rows, single conv (3+2R)
constexpr int AVR2 = 43;     // apron rows, fused (3+4R)
constexpr int BVR  = 23;     // b-tile rows
constexpr int PST  = 25;     // partials slot stride (odd -> conflict-free)
constexpr int P1L  = 46 * PST;   // 1150 words per conv1 level
constexpr int P2L  = 6 * PST;    // 150 words per conv2 level

__device__ __forceinline__ float wave_sum(float v) {
#pragma unroll
    for (int off = 32; off >= 1; off >>= 1) v += __shfl_xor(v, off);
    return v;
}

// wt[dy*24+dx] = exp(-100*C_ref(dy,dx)) from C row 1176 (pixel (24,24)).
template <bool WC, int NT>
__device__ __forceinline__ void stage_wt(float* wtl, float* wcl,
                                         const float* __restrict__ C) {
    for (int i = threadIdx.x; i < WIN * WPAD; i += NT) {
        const int dy = i / WPAD, dx = i - dy * WPAD;
        float wv = 0.f, wc = 0.f;
        if (dx < WIN) {
            const float c = C[1176 * N + (14 + dy) * 48 + (14 + dx)];
            wv = __expf(c * -100.f);
            wc = wv * c;
        }
        wtl[i] = wv;
        if (WC) wcl[i] = wc;
    }
}

// Stage apron rows [ytop, ytop+nrows) x cols -12..59 (aligned float4).
template <bool ONES, int NT>
__device__ __forceinline__ void stage_ap(float* vl, const float* img,
                                         int b, int ytop, int nrows) {
    for (int i = threadIdx.x; i < nrows * 18; i += NT) {
        const int rr = i / 18, c4 = i - rr * 18;
        const int y = ytop + rr, x0 = c4 * 4 - APX;
        float4 v = make_float4(0.f, 0.f, 0.f, 0.f);
        if ((unsigned)y < 48u && (unsigned)x0 < 48u)
            v = ONES ? make_float4(1.f, 1.f, 1.f, 1.f)
                     : *(const float4*)(img + b * N + y * 48 + x0);
        *(float4*)&vl[rr * AST + c4 * 4] = v;
    }
}

// 12-wide tap-row (proven, single-conv kernels): acc[k] += wr[dx]*vp[k+2+dx].
__device__ __forceinline__ void conv_row(const float* vp, const float* wp,
                                         float* acc) {
    float vr[36], wr[24];
#pragma unroll
    for (int c = 0; c < 9; ++c) *(float4*)&vr[4 * c] = *(const float4*)&vp[4 * c];
#pragma unroll
    for (int c = 0; c < 6; ++c) *(float4*)&wr[4 * c] = *(const float4*)&wp[4 * c];
#pragma unroll
    for (int dx = 0; dx < WIN; ++dx)
#pragma unroll
        for (int k = 0; k < 12; ++k)
            acc[k] = fmaf(wr[dx], vr[k + 2 + dx], acc[k]);
}

// 24-wide tap-row (fused): acc[k] += wr[dx]*vp[k+2+dx], k<24, dx<21.
__device__ __forceinline__ void conv_row24(const float* vp, const float* wp,
                                           float* acc) {
    float vr[48], wr[24];
#pragma unroll
    for (int c = 0; c < 12; ++c) *(float4*)&vr[4 * c] = *(const float4*)&vp[4 * c];
#pragma unroll
    for (int c = 0; c < 6; ++c) *(float4*)&wr[4 * c] = *(const float4*)&wp[4 * c];
#pragma unroll
    for (int dx = 0; dx < WIN; ++dx)
#pragma unroll
        for (int k = 0; k < 24; ++k)
            acc[k] = fmaf(wr[dx], vr[k + 2 + dx], acc[k]);
}

// ------------------------------------------------------------- a1 ---------
// rowsum = K*1; A0 = softmax/rowsum; smstat; out=0.
__global__ __launch_bounds__(256) void sk_a1(const float* __restrict__ logits,
                                             const float* __restrict__ C,
                                             float* __restrict__ smstat,
                                             float* __restrict__ A0,
                                             float* __restrict__ out) {
    __shared__ float vl[AVR1 * AST];
    __shared__ float wtl[WIN * WPAD];
    __shared__ float part[NTH * 12];
    __shared__ float sred[8];

    const int bid = blockIdx.x;
    const int b   = bid & 15;
    const int y0  = (bid >> 4) * 3;
    const int tid = threadIdx.x, w = tid >> 6, lane = tid & 63;

    stage_wt<false, 256>(wtl, nullptr, C);
    stage_ap<true, 256>(vl, nullptr, b, y0 - R, AVR1);

    float xs[9];
    float m = -3.0e38f;
#pragma unroll
    for (int s9 = 0; s9 < 9; ++s9) {
        xs[s9] = logits[b * N + s9 * 256 + tid];
        m = fmaxf(m, xs[s9]);
    }
#pragma unroll
    for (int off = 32; off >= 1; off >>= 1) m = fmaxf(m, __shfl_xor(m, off));
    if (lane == 0) sred[w] = m;
    __syncthreads();
    m = fmaxf(fmaxf(sred[0], sred[1]), fmaxf(sred[2], sred[3]));
    float sum = 0.f;
#pragma unroll
    for (int s9 = 0; s9 < 9; ++s9) sum += __expf(xs[s9] - m);
#pragma unroll
    for (int off = 32; off >= 1; off >>= 1) sum += __shfl_xor(sum, off);
    __syncthreads();
    if (lane == 0) sred[4 + w] = sum;
    __syncthreads();
    sum = sred[4] + sred[5] + sred[6] + sred[7];
    const float sm_m = m, sm_inv = 1.f / sum;
    if (tid == 0 && (bid >> 4) == 0) {
        smstat[2 * b]     = sm_m;
        smstat[2 * b + 1] = sm_inv;
        if (b == 0) out[0] = 0.f;
    }
    __syncthreads();

    if (tid < NTH) {
        const int dy = tid / 12, strip = tid - dy * 12;
        const int r = strip >> 2, xw = (strip & 3) * 12;
        float acc[12];
#pragma unroll
        for (int k = 0; k < 12; ++k) acc[k] = 0.f;
        conv_row(&vl[(r + dy) * AST + xw], &wtl[dy * WPAD], acc);
#pragma unroll
        for (int c = 0; c < 3; ++c)
            *(float4*)&part[tid * 12 + 4 * c] = *(float4*)&acc[4 * c];
    }
    __syncthreads();

    if (tid < NOUT) {
        float ssum = 0.f;
#pragma unroll
        for (int d = 0; d < WIN; ++d) ssum += part[d * 144 + tid];
        const int o = b * N + (y0 + tid / 48) * 48 + (tid % 48);
        A0[o] = __expf(logits[o] - sm_m) * sm_inv / ssum;
    }
}

// ------------------------------------------------------------- fused ------
// conv1: 506 tasks (dy2<11, rb<23, xg<2), 1/thread, 24-wide; scalar partials
// at stride-25 slots; reduce -> b-tile; conv2: 66 tasks; a-update. 4 syncs.
__global__ __launch_bounds__(512) void sk_fused(const float* __restrict__ logits,
                                                const float* __restrict__ target,
                                                const float* __restrict__ C,
                                                const float* __restrict__ smstat,
                                                const float* __restrict__ Ain,
                                                float* __restrict__ Aout) {
    __shared__ float vl[AVR2 * AST];    // 13072 B
    __shared__ float bt[BVR * AST];     //  6992 B
    __shared__ float part[11 * P1L];    // 50600 B
    __shared__ float wtl[WIN * WPAD];   //  2016 B

    const int bid = blockIdx.x;
    const int b   = bid & 15;
    const int y0  = (bid >> 4) * 3;
    const int tid = threadIdx.x;

    stage_ap<false, 512>(vl, Ain, b, y0 - 2 * R, AVR2);   // long-latency first
    stage_wt<false, 512>(wtl, nullptr, C);
    for (int i = tid; i < (BVR * AST) / 4; i += 512)
        *(float4*)&bt[4 * i] = make_float4(0.f, 0.f, 0.f, 0.f);
    const float sm_m = smstat[2 * b], sm_inv = smstat[2 * b + 1];
    __syncthreads();

    // ---- conv1: tau = dy2*46 + rb*2 + xg ----------------------------------
    if (tid < 506) {
        const int dy2 = tid / 46, rem = tid - dy2 * 46;
        const int rb = rem >> 1, xg = rem & 1;
        float acc[24];
#pragma unroll
        for (int k = 0; k < 24; ++k) acc[k] = 0.f;
        conv_row24(&vl[(rb + 2 * dy2) * AST + xg * 24],
                   &wtl[(2 * dy2) * WPAD], acc);
        if (dy2 < 10)
            conv_row24(&vl[(rb + 2 * dy2 + 1) * AST + xg * 24],
                       &wtl[(2 * dy2 + 1) * WPAD], acc);
        float* pp = &part[dy2 * P1L + (rb * 2 + xg) * PST];
#pragma unroll
        for (int k = 0; k < 24; ++k) pp[k] = acc[k];
    }
    __syncthreads();

    // ---- reduce 11 levels -> b-tile interior ------------------------------
    for (int o = tid; o < BVR * 48; o += 512) {
        const int rb = o / 48, x = o - rb * 48;
        const int slot = rb * 2 + (x >= 24 ? 1 : 0);
        const int k = x >= 24 ? x - 24 : x;
        float s = 0.f;
#pragma unroll
        for (int d = 0; d < 11; ++d) s += part[d * P1L + slot * PST + k];
        const int ybg = y0 - R + rb;
        if ((unsigned)ybg < 48u)
            bt[rb * AST + APX + x] = (target[b * N + ybg * 48 + x] + 1e-8f) / s;
    }
    __syncthreads();

    // ---- conv2: 66 tasks (dy2<11, ra<3, xg<2) -----------------------------
    if (tid < 66) {
        const int dy2 = tid / 6, rem = tid - dy2 * 6;
        const int ra = rem >> 1, xg = rem & 1;
        float acc[24];
#pragma unroll
        for (int k = 0; k < 24; ++k) acc[k] = 0.f;
        conv_row24(&bt[(ra + 2 * dy2) * AST + xg * 24],
                   &wtl[(2 * dy2) * WPAD], acc);
        if (dy2 < 10)
            conv_row24(&bt[(ra + 2 * dy2 + 1) * AST + xg * 24],
                       &wtl[(2 * dy2 + 1) * WPAD], acc);
        float* pp = &part[dy2 * P2L + (ra * 2 + xg) * PST];
#pragma unroll
        for (int k = 0; k < 24; ++k) pp[k] = acc[k];
    }
    __syncthreads();

    if (tid < NOUT) {
        const int ra = tid / 48, x = tid - ra * 48;
        const int slot = ra * 2 + (x >= 24 ? 1 : 0);
        const int k = x >= 24 ? x - 24 : x;
        float ssum = 0.f;
#pragma unroll
        for (int d = 0; d < 11; ++d) ssum += part[d * P2L + slot * PST + k];
        const int o = b * N + (y0 + ra) * 48 + x;
        Aout[o] = __expf(logits[o] - sm_m) * sm_inv / ssum;
    }
}

// ------------------------------------------------------------- cost -------
// s1 = K a10, s2 = (K.C) a10; val = (target+1e-8)/s1*s2; atomicAdd /16.
__global__ __launch_bounds__(256) void sk_cost(const float* __restrict__ target,
                                               const float* __restrict__ C,
                                               const float* __restrict__ Ain,
                                               float* __restrict__ out) {
    __shared__ float vl[AVR1 * AST];
    __shared__ float wtl[WIN * WPAD], wcl[WIN * WPAD];
    __shared__ float p1[NTH * 12], p2[NTH * 12];
    __shared__ float sred[4];

    const int bid = blockIdx.x;
    const int b   = bid & 15;
    const int y0  = (bid >> 4) * 3;
    const int tid = threadIdx.x, w = tid >> 6, lane = tid & 63;

    stage_wt<true, 256>(wtl, wcl, C);
    stage_ap<false, 256>(vl, Ain, b, y0 - R, AVR1);
    __syncthreads();

    if (tid < NTH) {
        const int dy = tid / 12, strip = tid - dy * 12;
        const int r = strip >> 2, xw = (strip & 3) * 12;
        float a1[12], a2[12];
#pragma unroll
        for (int k = 0; k < 12; ++k) { a1[k] = 0.f; a2[k] = 0.f; }
        float vr[36], wr[24], cr[24];
        const float* vp = &vl[(r + dy) * AST + xw];
#pragma unroll
        for (int c = 0; c < 9; ++c)
            *(float4*)&vr[4 * c] = *(const float4*)&vp[4 * c];
#pragma unroll
        for (int c = 0; c < 6; ++c) {
            *(float4*)&wr[4 * c] = *(const float4*)&wtl[dy * WPAD + 4 * c];
            *(float4*)&cr[4 * c] = *(const float4*)&wcl[dy * WPAD + 4 * c];
        }
#pragma unroll
        for (int dx = 0; dx < WIN; ++dx)
#pragma unroll
            for (int k = 0; k < 12; ++k) {
                a1[k] = fmaf(wr[dx], vr[k + 2 + dx], a1[k]);
                a2[k] = fmaf(cr[dx], vr[k + 2 + dx], a2[k]);
            }
#pragma unroll
        for (int c = 0; c < 3; ++c) {
            *(float4*)&p1[tid * 12 + 4 * c] = *(float4*)&a1[4 * c];
            *(float4*)&p2[tid * 12 + 4 * c] = *(float4*)&a2[4 * c];
        }
    }
    __syncthreads();

    float val = 0.f;
    if (tid < NOUT) {
        float s1 = 0.f, s2 = 0.f;
#pragma unroll
        for (int d = 0; d < WIN; ++d) {
            s1 += p1[d * 144 + tid];
            s2 += p2[d * 144 + tid];
        }
        const int o = b * N + (y0 + tid / 48) * 48 + (tid % 48);
        val = (target[o] + 1e-8f) / s1 * s2;
    }
    val = wave_sum(val);
    if (lane == 0) sred[w] = val;
    __syncthreads();
    if (tid == 0)
        atomicAdd(out, (sred[0] + sred[1] + sred[2] + sred[3]) * (1.f / 16.f));
}

}  // namespace

extern "C" void kernel_launch(void* const* d_in, const int* in_sizes, int n_in,
                              void* d_out, int out_size, void* d_ws, size_t ws_size,
                              hipStream_t stream) {
    const float* logits = (const float*)d_in[0];   // (B, 48, 48)
    const float* target = (const float*)d_in[1];   // (B, 48, 48)
    const float* C      = (const float*)d_in[2];   // (1, N, N)
    float* out = (float*)d_out;
    float* ws  = (float*)d_ws;

    float* smstat = ws;            // [32]
    float* A0     = ws + 32;       // [B][N]
    float* A1     = A0 + NB;       // [B][N]

    sk_a1<<<256, 256, 0, stream>>>(logits, C, smstat, A0, out);

    // 9 fused (b_t, a_{t+1}) dispatches, ping-pong; a10 lands in A1
    float* bufs[2] = {A0, A1};
    for (int t = 0; t < 9; ++t) {
        sk_fused<<<256, 512, 0, stream>>>(logits, target, C, smstat,
                                          bufs[t & 1], bufs[(t & 1) ^ 1]);
    }

    sk_cost<<<256, 256, 0, stream>>>(target, C, A1, out);
}